// Round 11
// baseline (156.475 us; speedup 1.0000x reference)
//
#include <hip/hip_runtime.h>

typedef unsigned long long u64;

#define CC 32
#define NN 512
#define TT 12
#define BB 8
#define QTOT (4*CC*NN)        // 65536 bias (k,ch,n) pairs
#define NELEM (BB*CC*NN)      // 131072

__device__ __forceinline__ float eluf(float x){ return x>0.f ? x : (__expf(x)-1.f); }
__device__ __forceinline__ float elu3f(float x){ return eluf(eluf(eluf(x))); }
__device__ __forceinline__ float sigmf(float x){
  if (x>=0.f) return 1.f/(1.f+__expf(-x));
  float e=__expf(x); return e/(1.f+e);
}
__device__ __forceinline__ float tanhff(float x){
  return 1.f - 2.f/(__expf(2.f*x)+1.f);   // exact at saturation
}

// ============================ FAST PATH ====================================
// K1: bias (4,C,N,T) -> tb[T][4][C][N]  (coalesced per-step reads later)
__global__ __launch_bounds__(256, 4)
void k_transpose_bias(const float* __restrict__ bg, float* __restrict__ tb){
  int q = blockIdx.x*256 + threadIdx.x;     // 0..65535
  const float4* p = (const float4*)(bg + q*12);
  float4 a = p[0], d = p[1], e = p[2];
  tb[ 0*QTOT + q] = a.x;  tb[ 1*QTOT + q] = a.y;
  tb[ 2*QTOT + q] = a.z;  tb[ 3*QTOT + q] = a.w;
  tb[ 4*QTOT + q] = d.x;  tb[ 5*QTOT + q] = d.y;
  tb[ 6*QTOT + q] = d.z;  tb[ 7*QTOT + q] = d.w;
  tb[ 8*QTOT + q] = e.x;  tb[ 9*QTOT + q] = e.y;
  tb[10*QTOT + q] = e.z;  tb[11*QTOT + q] = e.w;
}

// K2: the recurrence. One block per batch, 1024 threads, ZERO fabric hops.
// Thread t: ch = t>>5, n-block nb = (t&31)*16 (16 consecutive n).
__global__ __launch_bounds__(1024, 1)
void k_glstm_batch(const float* __restrict__ xg,     // (B,C,N,T)
                   const float* __restrict__ cellg,  // (B,C,N)
                   const float* __restrict__ w1g,    // (T,8,C,C)
                   const float* __restrict__ w2g,    // (T,8,C,C)
                   const float* __restrict__ tb,     // [T][4][C][N]
                   float* __restrict__ chist,        // [T][B][C][N]
                   float* __restrict__ g2h,          // [T][B][C]
                   float* __restrict__ outg)         // final cell written here
{
  __shared__ float w1L[8][CC][CC];   // [m][j][i]   32KB
  __shared__ float w2L[8][CC][CC];   // [m][i][ch]  32KB
  __shared__ float xsumL[TT][CC];
  __shared__ float csumL[CC];
  __shared__ float outLh[8][CC];

  const int b    = blockIdx.x;
  const int t    = threadIdx.x;
  const int ch   = t >> 5;
  const int nsub = t & 31;
  const int nb   = nsub << 4;
  const int wv   = t >> 6;
  const int grow = (b*CC + ch)*NN + nb;

  // cell -> registers (16 elements)
  const float4* cp4 = (const float4*)(cellg + grow);
  float4 c0 = cp4[0], c1 = cp4[1], c2 = cp4[2], c3 = cp4[3];

  // x rowsums per t (768B contiguous per thread) + csum(state0)
  float xs[TT];
  #pragma unroll
  for (int k=0;k<TT;k++) xs[k]=0.f;
  const float4* xp = (const float4*)(xg + grow*TT);
  #pragma unroll
  for (int j=0;j<16;j++){
    float4 a=xp[j*3+0], d=xp[j*3+1], e=xp[j*3+2];
    xs[0]+=a.x; xs[1]+=a.y; xs[2]+=a.z;  xs[3]+=a.w;
    xs[4]+=d.x; xs[5]+=d.y; xs[6]+=d.z;  xs[7]+=d.w;
    xs[8]+=e.x; xs[9]+=e.y; xs[10]+=e.z; xs[11]+=e.w;
  }
  float cs0 = (c0.x+c0.y+c0.z+c0.w)+(c1.x+c1.y+c1.z+c1.w)
            + (c2.x+c2.y+c2.z+c2.w)+(c3.x+c3.y+c3.z+c3.w);
  #pragma unroll
  for (int off=16; off>=1; off>>=1){
    #pragma unroll
    for (int k=0;k<TT;k++) xs[k] += __shfl_xor(xs[k], off, 32);
    cs0 += __shfl_xor(cs0, off, 32);
  }
  if (nsub == 0){
    #pragma unroll
    for (int k=0;k<TT;k++) xsumL[k][ch] = xs[k];
    csumL[ch] = cs0;
  }

  // stage w1/w2 for s=0 (16K floats, 2 float4 each per thread per matrix)
  {
    const float4* p1 = (const float4*)(w1g);
    const float4* p2 = (const float4*)(w2g);
    float4* d1 = (float4*)&w1L[0][0][0];
    float4* d2 = (float4*)&w2L[0][0][0];
    d1[t] = p1[t]; d1[t+1024] = p1[t+1024];
    d2[t] = p2[t]; d2[t+1024] = p2[t+1024];
  }
  __syncthreads();

  for (int s=0; s<TT; ++s){
    // ---- phase 1: heads (waves 0-3; lane (m,i) computes head m, col i) ----
    if (wv < 4){
      const int m  = t >> 5;     // 0..7
      const int ii = t & 31;
      const float* zrow = (m < 4) ? &xsumL[s][0] : &csumL[0];  // x vs c head
      const float* w1c = &w1L[m][0][ii];
      float s1 = 0.f;
      #pragma unroll
      for (int j=0;j<32;j++) s1 = fmaf(zrow[j], w1c[j*CC], s1);
      float h1 = eluf(eluf(s1));
      const float* w2c = &w2L[m][0][ii];
      float pp = 0.f;
      #pragma unroll
      for (int j=0;j<32;j++) pp = fmaf(__shfl(h1, j, 32), w2c[j*CC], pp);
      outLh[m][ii] = elu3f(512.f*pp);
    }
    __syncthreads();   // B1: outLh ready; w slab free for restage

    const float g0 = outLh[0][ch] + outLh[4][ch];
    const float g1 = outLh[1][ch] + outLh[5][ch];
    const float g2 = outLh[2][ch] + outLh[6][ch];
    const float g3 = outLh[3][ch] + outLh[7][ch];

    // issue next-step w loads early (latency hides under the gate math)
    float4 w1a, w1b, w2a, w2b;
    if (s < TT-1){
      const float4* p1 = (const float4*)(w1g + (s+1)*8*CC*CC);
      const float4* p2 = (const float4*)(w2g + (s+1)*8*CC*CC);
      w1a = p1[t]; w1b = p1[t+1024];
      w2a = p2[t]; w2b = p2[t+1024];
    }

    // ---- phase 2: gates (c-part only; H deferred to K3) ----
    const float* tbs = tb + s*QTOT;
    float csp = 0.f;
    float* chp = chist + s*NELEM + grow;
    #pragma unroll
    for (int q=0;q<4;q++){
      float4 b0v = *(const float4*)(tbs + (0*CC+ch)*NN + nb + q*4);
      float4 b1v = *(const float4*)(tbs + (1*CC+ch)*NN + nb + q*4);
      float4 b3v = *(const float4*)(tbs + (3*CC+ch)*NN + nb + q*4);
      float4* cq = (q==0)?&c0:(q==1)?&c1:(q==2)?&c2:&c3;
      float ig,fg,ct;
      ig = sigmf(g0 + b0v.x); fg = sigmf(g1 + b1v.x); ct = tanhff(g3 + b3v.x);
      cq->x = fg*cq->x + ig*ct;
      ig = sigmf(g0 + b0v.y); fg = sigmf(g1 + b1v.y); ct = tanhff(g3 + b3v.y);
      cq->y = fg*cq->y + ig*ct;
      ig = sigmf(g0 + b0v.z); fg = sigmf(g1 + b1v.z); ct = tanhff(g3 + b3v.z);
      cq->z = fg*cq->z + ig*ct;
      ig = sigmf(g0 + b0v.w); fg = sigmf(g1 + b1v.w); ct = tanhff(g3 + b3v.w);
      cq->w = fg*cq->w + ig*ct;
      ((float4*)chp)[q] = *cq;                  // coalesced c-history
      csp += cq->x + cq->y + cq->z + cq->w;
    }

    // csum for next step (half-wave reduce, fixed order -> deterministic)
    #pragma unroll
    for (int off=16; off>=1; off>>=1) csp += __shfl_xor(csp, off, 32);
    if (nsub == 0){
      csumL[ch] = csp;
      g2h[s*BB*CC + b*CC + ch] = g2;
    }

    // write staged w (readers finished at B1; next read is after B2)
    if (s < TT-1){
      float4* d1 = (float4*)&w1L[0][0][0];
      float4* d2 = (float4*)&w2L[0][0][0];
      d1[t] = w1a; d1[t+1024] = w1b;
      d2[t] = w2a; d2[t+1024] = w2b;
    }
    __syncthreads();  // B2: csumL/w ready for next step
  }

  // final cell state
  float4* cf = (float4*)(outg + BB*CC*NN*TT + grow);
  cf[0]=c0; cf[1]=c1; cf[2]=c2; cf[3]=c3;
}

// K3: H finalize over the whole device: H = sigm(g2+b2) * tanh(c_hist)
__global__ __launch_bounds__(256, 4)
void k_hfinal(const float* __restrict__ chist,   // [T][B][C][N]
              const float* __restrict__ tb,      // [T][4][C][N]
              const float* __restrict__ g2h,     // [T][B][C]
              float* __restrict__ outg)          // (B,C,N,T)
{
  int gid = blockIdx.x*256 + threadIdx.x;        // 0..131071 = (b,ch,n) flat
  int bch = gid >> 9;                            // b*32+ch
  int ch  = bch & 31;
  int n   = gid & 511;
  float hm[TT];
  #pragma unroll
  for (int s=0;s<TT;s++){
    float c  = chist[s*NELEM + gid];
    float b2 = tb[s*QTOT + (2*CC+ch)*NN + n];
    float g2 = g2h[s*BB*CC + bch];
    hm[s] = sigmf(g2 + b2) * tanhff(c);
  }
  float4* op = (float4*)(outg + gid*TT);
  op[0] = make_float4(hm[0], hm[1], hm[2],  hm[3]);
  op[1] = make_float4(hm[4], hm[5], hm[6],  hm[7]);
  op[2] = make_float4(hm[8], hm[9], hm[10], hm[11]);
}

// ====================== FALLBACK: r8 kernel (proven 43.5us) ================
#define NBLK8 256
#define NTHR8 256
__device__ __forceinline__ u64 pack_slot(unsigned tag, float v){
  return ((u64)tag<<32) | (u64)__float_as_uint(v);
}
__device__ __forceinline__ u64 ld_slot(u64* p){
  return __hip_atomic_load(p, __ATOMIC_RELAXED, __HIP_MEMORY_SCOPE_AGENT);
}
__device__ __forceinline__ void xch_slot(u64* p, u64 v){
  (void)__hip_atomic_exchange(p, v, __ATOMIC_RELAXED, __HIP_MEMORY_SCOPE_AGENT);
}
__device__ __forceinline__ float poll_slot(u64* p, unsigned want){
  u64 v = ld_slot(p);
  int guard = 0;
  while ((unsigned)(v>>32) != want){
    __builtin_amdgcn_s_sleep(1);
    v = ld_slot(p);
    if (++guard > 1000000) break;
  }
  return __uint_as_float((unsigned)v);
}

__global__ __launch_bounds__(NTHR8, 1)
void glstm_fused_r8(const float* __restrict__ xg, const float* __restrict__ cellg,
                    const float* __restrict__ w1g, const float* __restrict__ w2g,
                    const float* __restrict__ biasg, float* __restrict__ outg,
                    u64* slots)
{
  __shared__ float biasL[4][TT][NN];
  __shared__ float preS[2][4];
  __shared__ float redS[2][4];
  __shared__ float wpart[13][4];

  const int blk  = blockIdx.x;
  const int bb   = blk >> 5;
  const int ch   = blk & 31;
  const int row  = blk;
  const int tid  = threadIdx.x;
  const int lane = tid & 63;
  const int wv   = tid >> 6;
  const int i0   = lane & 31;

  u64* cs_slot = slots;
  u64* xs_slot = slots + 2*NBLK8;

  const int n0 = 2*tid;
  float2 cc2 = *(const float2*)(cellg + row*NN + n0);
  float c0 = cc2.x, c1 = cc2.y;

  float xs[TT];
  #pragma unroll
  for (int k=0;k<TT;k++) xs[k]=0.f;
  const float* xrow = xg + row*NN*TT;
  #pragma unroll
  for (int half=0; half<2; half++){
    int n = tid + half*256;
    const float4* p = (const float4*)(xrow + n*TT);
    float4 v0=p[0], v1=p[1], v2=p[2];
    xs[0]+=v0.x;  xs[1]+=v0.y;  xs[2]+=v0.z;  xs[3]+=v0.w;
    xs[4]+=v1.x;  xs[5]+=v1.y;  xs[6]+=v1.z;  xs[7]+=v1.w;
    xs[8]+=v2.x;  xs[9]+=v2.y;  xs[10]+=v2.z; xs[11]+=v2.w;
  }
  float cp = c0 + c1;
  #pragma unroll
  for (int off=32; off>=1; off>>=1){
    #pragma unroll
    for (int k=0;k<TT;k++) xs[k] += __shfl_xor(xs[k], off, 64);
    cp += __shfl_xor(cp, off, 64);
  }
  if (lane == 0){
    #pragma unroll
    for (int k=0;k<TT;k++) wpart[k][wv] = xs[k];
    wpart[12][wv] = cp;
  }
  __syncthreads();
  if (tid < 13){
    float v = wpart[tid][0]+wpart[tid][1]+wpart[tid][2]+wpart[tid][3];
    if (tid < TT) xch_slot(&xs_slot[tid*NBLK8 + row], pack_slot(1u, v));
    else          xch_slot(&cs_slot[row],             pack_slot(1u, v));
  }
  #pragma unroll
  for (int k=0;k<4;k++){
    #pragma unroll
    for (int half=0; half<2; half++){
      int n = tid + half*256;
      const float4* p = (const float4*)(biasg + ((k*CC + ch)*NN + n)*TT);
      float4 v0=p[0], v1=p[1], v2=p[2];
      biasL[k][0][n]=v0.x;  biasL[k][1][n]=v0.y;  biasL[k][2][n]=v0.z;  biasL[k][3][n]=v0.w;
      biasL[k][4][n]=v1.x;  biasL[k][5][n]=v1.y;  biasL[k][6][n]=v1.z;  biasL[k][7][n]=v1.w;
      biasL[k][8][n]=v2.x;  biasL[k][9][n]=v2.y;  biasL[k][10][n]=v2.z; biasL[k][11][n]=v2.w;
    }
  }
  const int m = wv + ((lane >> 5) << 2);
  float w1p[2][32];
  float w2p[2];
  {
    const float* w1m = w1g + m*CC*CC + i0;
    #pragma unroll
    for (int j=0;j<32;j++) w1p[0][j] = w1m[j*CC];
    w2p[0] = w2g[(m*CC + i0)*CC + ch];
  }
  float zxr[TT];
  #pragma unroll
  for (int k=0;k<TT;k++)
    zxr[k] = poll_slot(&xs_slot[k*NBLK8 + bb*CC + i0], 1u);

  float hm0[TT], hm1[TT];
  #pragma unroll
  for (int s=0;s<TT;s++){
    float csv = poll_slot(&cs_slot[(s&1)*NBLK8 + bb*CC + i0], (unsigned)(s+1));
    float zs = (lane < 32) ? zxr[s] : csv;
    float pa = 0.f, pb = 0.f;
    #pragma unroll
    for (int j=0;j<16;j++){
      pa = fmaf(__shfl(zs, j,    32), w1p[s&1][j],    pa);
      pb = fmaf(__shfl(zs, j+16, 32), w1p[s&1][j+16], pb);
    }
    float s1 = pa + pb;
    float h1 = eluf(eluf(s1));
    float pp = h1 * w2p[s&1];
    #pragma unroll
    for (int off=16; off>=1; off>>=1) pp += __shfl_xor(pp, off, 32);
    float ov = elu3f(512.f*pp);
    float prew = ov + __shfl_xor(ov, 32, 64);
    if (lane == 0) preS[s&1][wv] = prew;

    float b00 = biasL[0][s][n0], b01 = biasL[0][s][n0+1];
    float b10 = biasL[1][s][n0], b11 = biasL[1][s][n0+1];
    float b20 = biasL[2][s][n0], b21 = biasL[2][s][n0+1];
    float b30 = biasL[3][s][n0], b31 = biasL[3][s][n0+1];

    __syncthreads();
    const float g0 = preS[s&1][0], g1 = preS[s&1][1];
    const float g2 = preS[s&1][2], g3 = preS[s&1][3];

    float ig0 = sigmf(g0 + b00);
    float fg0 = sigmf(g1 + b10);
    float ct0 = tanhff(g3 + b30);
    float ig1 = sigmf(g0 + b01);
    float fg1 = sigmf(g1 + b11);
    float ct1 = tanhff(g3 + b31);
    c0 = fg0*c0 + ig0*ct0;
    c1 = fg1*c1 + ig1*ct1;

    if (s < TT-1){
      const int par = (s+1)&1;
      float csp = c0 + c1;
      #pragma unroll
      for (int off=32; off>=1; off>>=1) csp += __shfl_xor(csp, off, 64);
      if (lane == 0) redS[par][wv] = csp;
      __syncthreads();
      if (tid == 0){
        float tot = redS[par][0]+redS[par][1]+redS[par][2]+redS[par][3];
        xch_slot(&cs_slot[par*NBLK8 + row], pack_slot((unsigned)(s+2), tot));
      }
      const float* w1m = w1g + ((s+1)*8 + m)*CC*CC + i0;
      #pragma unroll
      for (int j=0;j<32;j++) w1p[par][j] = w1m[j*CC];
      w2p[par] = w2g[(((s+1)*8 + m)*CC + i0)*CC + ch];
    }
    hm0[s] = sigmf(g2 + b20) * tanhff(c0);
    hm1[s] = sigmf(g2 + b21) * tanhff(c1);
  }
  float4* op = (float4*)(outg + (row*NN + n0)*TT);
  op[0] = make_float4(hm0[0], hm0[1], hm0[2],  hm0[3]);
  op[1] = make_float4(hm0[4], hm0[5], hm0[6],  hm0[7]);
  op[2] = make_float4(hm0[8], hm0[9], hm0[10], hm0[11]);
  op[3] = make_float4(hm1[0], hm1[1], hm1[2],  hm1[3]);
  op[4] = make_float4(hm1[4], hm1[5], hm1[6],  hm1[7]);
  op[5] = make_float4(hm1[8], hm1[9], hm1[10], hm1[11]);
  *(float2*)(outg + NBLK8*NN*TT + row*NN + n0) = make_float2(c0, c1);
}

// ============================== LAUNCH =====================================
extern "C" void kernel_launch(void* const* d_in, const int* in_sizes, int n_in,
                              void* d_out, int out_size, void* d_ws, size_t ws_size,
                              hipStream_t stream)
{
  (void)in_sizes; (void)n_in; (void)out_size;
  // setup_inputs order: input, cell, adj, w1, a1, w2, a2, bias
  const float* xg    = (const float*)d_in[0];
  const float* cellg = (const float*)d_in[1];
  const float* w1g   = (const float*)d_in[3];
  const float* w2g   = (const float*)d_in[5];
  const float* biasg = (const float*)d_in[7];
  float* outg = (float*)d_out;

  const size_t tb_f    = (size_t)TT*QTOT;        // 786432 floats
  const size_t chist_f = (size_t)TT*NELEM;       // 1572864 floats
  const size_t g2_f    = (size_t)TT*BB*CC;       // 3072 floats
  const size_t need    = (tb_f + chist_f + g2_f)*sizeof(float);   // ~9.44MB

  if (ws_size >= need){
    float* tb    = (float*)d_ws;
    float* chist = tb + tb_f;
    float* g2h   = chist + chist_f;
    k_transpose_bias<<<dim3(QTOT/256), dim3(256), 0, stream>>>(biasg, tb);
    k_glstm_batch<<<dim3(BB), dim3(1024), 0, stream>>>(xg, cellg, w1g, w2g,
                                                       tb, chist, g2h, outg);
    k_hfinal<<<dim3(NELEM/256), dim3(256), 0, stream>>>(chist, tb, g2h, outg);
  } else {
    // fallback: proven r8 spin-pipeline kernel
    u64* slots = (u64*)d_ws;
    hipMemsetAsync(d_ws, 0, (size_t)(2*NBLK8 + TT*NBLK8)*sizeof(u64), stream);
    glstm_fused_r8<<<dim3(NBLK8), dim3(NTHR8), 0, stream>>>(xg, cellg, w1g, w2g,
                                                            biasg, outg, slots);
  }
}

// Round 12
// 46.288 us; speedup vs baseline: 3.3805x; 3.3805x over previous
//
#include <hip/hip_runtime.h>

typedef unsigned long long u64;

#define CC 32
#define NN 512
#define TT 12
#define NBLK 256     // one block per (batch, channel); == CU count
#define NTHR 256     // 2 n-elements per thread (proven shape)

__device__ __forceinline__ float eluf(float x){ return x>0.f ? x : (__expf(x)-1.f); }
__device__ __forceinline__ float elu3f(float x){ return eluf(eluf(eluf(x))); }
__device__ __forceinline__ float sigmf(float x){
  if (x>=0.f) return 1.f/(1.f+__expf(-x));
  float e=__expf(x); return e/(1.f+e);
}
__device__ __forceinline__ float tanhff(float x){
  return 1.f - 2.f/(__expf(2.f*x)+1.f);   // exact at saturation
}
__device__ __forceinline__ u64 pack_slot(unsigned tag, float v){
  return ((u64)tag<<32) | (u64)__float_as_uint(v);
}
// ---- slow path (L3 coherence point; proven r1-r8) ----
__device__ __forceinline__ u64 ld_slot(u64* p){
  return __hip_atomic_load(p, __ATOMIC_RELAXED, __HIP_MEMORY_SCOPE_AGENT);
}
__device__ __forceinline__ void xch_slot(u64* p, u64 v){
  (void)__hip_atomic_exchange(p, v, __ATOMIC_RELAXED, __HIP_MEMORY_SCOPE_AGENT);
}
__device__ __forceinline__ float poll_slot(u64* p, unsigned want){
  u64 v = ld_slot(p);
  int guard = 0;
  while ((unsigned)(v>>32) != want){
    __builtin_amdgcn_s_sleep(1);
    v = ld_slot(p);
    if (++guard > 1000000) break;   // terminates instead of hanging
  }
  return __uint_as_float((unsigned)v);
}
// ---- fast path: same-XCD L2. Producer: plain store (write-back local L2).
//      Consumer: sc0 load (bypass L1, hit shared L2). 8B aligned = atomic.
__device__ __forceinline__ u64 l2_load(const u64* p){
  u64 v;
  asm volatile("global_load_dwordx2 %0, %1, off sc0\n\t"
               "s_waitcnt vmcnt(0)"
               : "=v"(v) : "v"(p) : "memory");
  return v;
}
__device__ __forceinline__ void l2_store(u64* p, u64 v){
  asm volatile("global_store_dwordx2 %0, %1, off"
               :: "v"(p), "v"(v) : "memory");
}
// Dual poll: fast every iter, L3 mirror every 16th (placement-agnostic).
__device__ __forceinline__ float poll_dual(const u64* fp, u64* sp, unsigned want){
  u64 v; int it = 0;
  for (;;){
    v = l2_load(fp);
    if ((unsigned)(v>>32) == want) break;
    if ((it & 15) == 15){
      v = ld_slot(sp);
      if ((unsigned)(v>>32) == want) break;
    }
    __builtin_amdgcn_s_sleep(1);
    if (++it > 1000000) break;      // terminates instead of hanging
  }
  return __uint_as_float((unsigned)v);
}

__global__ __launch_bounds__(NTHR, 1)
void glstm_fused(const float* __restrict__ xg,     // (B,C,N,T)
                 const float* __restrict__ cellg,  // (B,C,N)
                 const float* __restrict__ w1g,    // (T,8,C,C)
                 const float* __restrict__ w2g,    // (T,8,C,C)
                 const float* __restrict__ biasg,  // (4,C,N,T)
                 float* __restrict__ outg,         // (B,C,N,T) ++ (B,C,N)
                 u64* slots)
{
  // 96KB bias tile -> 1 block/CU (proven residency for the spin pipeline)
  __shared__ float biasL[4][TT][NN];
  __shared__ float preS[2][4];       // parity-buffered gate pre-activations
  __shared__ float redS[2][4];       // parity-buffered csum wave-partials
  __shared__ float wpart[13][4];

  const int blk  = blockIdx.x;
  const int b    = blk & 7;          // batch == XCD (blk%8 round-robin, m09)
  const int ch   = blk >> 3;
  const int row  = b*CC + ch;        // memory/slot row (layout fixed by problem)
  const int tid  = threadIdx.x;
  const int lane = tid & 63;
  const int wv   = tid >> 6;         // 0..3
  const int i0   = lane & 31;

  u64* scs = slots;                  // [2][NBLK] L3 csum mirror (memset-zeroed)
  u64* sxs = slots + 2*NBLK;         // [TT][NBLK] L3 xsum slots (memset-zeroed)
  u64* fcs = slots + 14*NBLK;        // [2][NBLK] FAST csum slots (L2, scrubbed)

  // ---- scrub own fast slots BEFORE first publish (same-L2 overwrite kills
  //      any stale/poison line; consumers can't see tag>=1 until tag1 L3
  //      publish, which is program-ordered after this + vmcnt drain) ----
  if (tid == 0){
    l2_store(&fcs[row], 0);
    l2_store(&fcs[NBLK + row], 0);
    asm volatile("s_waitcnt vmcnt(0)" ::: "memory");
  }

  // ---- per-thread state: 2 n-elements ----
  const int n0 = 2*tid;
  float2 cc2 = *(const float2*)(cellg + row*NN + n0);
  float c0 = cc2.x, c1 = cc2.y;

  // ---- x rowsums per t + csum(state0) FIRST (publish gates the batch group) ----
  float xs[TT];
  #pragma unroll
  for (int t=0;t<TT;t++) xs[t]=0.f;
  const float* xrow = xg + row*NN*TT;
  #pragma unroll
  for (int half=0; half<2; half++){
    int n = tid + half*256;
    const float4* p = (const float4*)(xrow + n*TT);
    float4 v0=p[0], v1=p[1], v2=p[2];
    xs[0]+=v0.x;  xs[1]+=v0.y;  xs[2]+=v0.z;  xs[3]+=v0.w;
    xs[4]+=v1.x;  xs[5]+=v1.y;  xs[6]+=v1.z;  xs[7]+=v1.w;
    xs[8]+=v2.x;  xs[9]+=v2.y;  xs[10]+=v2.z; xs[11]+=v2.w;
  }
  float cp = c0 + c1;
  #pragma unroll
  for (int off=32; off>=1; off>>=1){
    #pragma unroll
    for (int t=0;t<TT;t++) xs[t] += __shfl_xor(xs[t], off, 64);
    cp += __shfl_xor(cp, off, 64);
  }
  if (lane == 0){
    #pragma unroll
    for (int t=0;t<TT;t++) wpart[t][wv] = xs[t];
    wpart[12][wv] = cp;
  }
  __syncthreads();
  if (tid < 13){
    float v = wpart[tid][0]+wpart[tid][1]+wpart[tid][2]+wpart[tid][3];
    if (tid < TT){
      xch_slot(&sxs[tid*NBLK + row], pack_slot(1u, v));
    } else {
      // csum state0: step-0 consumers use the L3 mirror only (stale-refill
      // safety), but seed the fast slot too to keep its tag chain monotone.
      l2_store(&fcs[row], pack_slot(1u, v));
      xch_slot(&scs[row], pack_slot(1u, v));
    }
  }

  // ---- bias -> LDS (after publish; overlaps peers' publish latency) ----
  #pragma unroll
  for (int k=0;k<4;k++){
    #pragma unroll
    for (int half=0; half<2; half++){
      int n = tid + half*256;
      const float4* p = (const float4*)(biasg + ((k*CC + ch)*NN + n)*TT);
      float4 v0=p[0], v1=p[1], v2=p[2];
      biasL[k][0][n]=v0.x;  biasL[k][1][n]=v0.y;  biasL[k][2][n]=v0.z;  biasL[k][3][n]=v0.w;
      biasL[k][4][n]=v1.x;  biasL[k][5][n]=v1.y;  biasL[k][6][n]=v1.z;  biasL[k][7][n]=v1.w;
      biasL[k][8][n]=v2.x;  biasL[k][9][n]=v2.y;  biasL[k][10][n]=v2.z; biasL[k][11][n]=v2.w;
    }
  }

  // ---- head assignment + weight double-buffer (t=0 now) ----
  const int m = wv + ((lane >> 5) << 2);   // lanes<32: x-heads 0-3; lanes>=32: c-heads 4-7
  float w1p[2][32];
  float w2p[2];
  {
    const float* w1m = w1g + m*CC*CC + i0;
    #pragma unroll
    for (int j=0;j<32;j++) w1p[0][j] = w1m[j*CC];
    w2p[0] = w2g[(m*CC + i0)*CC + ch];
  }

  // ---- gather ALL peer xsums to registers once (L3 path; off critical loop) ----
  float zxr[TT];
  #pragma unroll
  for (int t=0;t<TT;t++)
    zxr[t] = poll_slot(&sxs[t*NBLK + b*CC + i0], 1u);

  // ---- 12 sequential steps, fully unrolled, 2 barriers/step ----
  float hm0[TT], hm1[TT];
  #pragma unroll
  for (int s=0;s<TT;s++){
    // hop: s=0 via L3 mirror (scrub-race safety); s>=1 via same-XCD L2 fast path
    float csv;
    if (s == 0) csv = poll_slot(&scs[b*CC + i0], 1u);
    else        csv = poll_dual(&fcs[(s&1)*NBLK + b*CC + i0],
                                &scs[(s&1)*NBLK + b*CC + i0], (unsigned)(s+1));
    float zs = (lane < 32) ? zxr[s] : csv;

    // head matvec from prefetched registers (no global loads post-poll)
    float pa = 0.f, pb = 0.f;
    #pragma unroll
    for (int j=0;j<16;j++){
      pa = fmaf(__shfl(zs, j,    32), w1p[s&1][j],    pa);
      pb = fmaf(__shfl(zs, j+16, 32), w1p[s&1][j+16], pb);
    }
    float s1 = pa + pb;
    float h1 = eluf(eluf(s1));
    float pp = h1 * w2p[s&1];
    #pragma unroll
    for (int off=16; off>=1; off>>=1) pp += __shfl_xor(pp, off, 32);
    float ov = elu3f(512.f*pp);
    float prew = ov + __shfl_xor(ov, 32, 64);      // x-head + c-head
    if (lane == 0) preS[s&1][wv] = prew;

    // bias -> regs before the barrier (gate phase = pure VALU)
    float b00 = biasL[0][s][n0], b01 = biasL[0][s][n0+1];
    float b10 = biasL[1][s][n0], b11 = biasL[1][s][n0+1];
    float b20 = biasL[2][s][n0], b21 = biasL[2][s][n0+1];
    float b30 = biasL[3][s][n0], b31 = biasL[3][s][n0+1];

    __syncthreads();   // B1: preS[s&1] ready
    const float g0 = preS[s&1][0], g1 = preS[s&1][1];
    const float g2 = preS[s&1][2], g3 = preS[s&1][3];

    float ig0 = sigmf(g0 + b00);
    float fg0 = sigmf(g1 + b10);
    float ct0 = tanhff(g3 + b30);
    float ig1 = sigmf(g0 + b01);
    float fg1 = sigmf(g1 + b11);
    float ct1 = tanhff(g3 + b31);
    c0 = fg0*c0 + ig0*ct0;
    c1 = fg1*c1 + ig1*ct1;

    if (s < TT-1){
      const int par = (s+1)&1;
      float csp = c0 + c1;
      #pragma unroll
      for (int off=32; off>=1; off>>=1) csp += __shfl_xor(csp, off, 64);
      if (lane == 0) redS[par][wv] = csp;
      __syncthreads(); // B2: redS ready (also fences preS for next parity reuse)
      if (tid == 0){
        float tot = redS[par][0]+redS[par][1]+redS[par][2]+redS[par][3];
        u64 pk = pack_slot((unsigned)(s+2), tot);
        l2_store(&fcs[par*NBLK + row], pk);   // fast: local L2, same-XCD readers
        xch_slot(&scs[par*NBLK + row], pk);   // mirror: L3 ground truth
      }
      // prefetch next step's weights AFTER the publish point
      const float* w1m = w1g + ((s+1)*8 + m)*CC*CC + i0;
      #pragma unroll
      for (int j=0;j<32;j++) w1p[par][j] = w1m[j*CC];
      w2p[par] = w2g[(((s+1)*8 + m)*CC + i0)*CC + ch];
    }

    hm0[s] = sigmf(g2 + b20) * tanhff(c0);
    hm1[s] = sigmf(g2 + b21) * tanhff(c1);
  }

  // ---- coalesced epilogue: 2 n-rows x 12 t contiguous ----
  float4* op = (float4*)(outg + (row*NN + n0)*TT);
  op[0] = make_float4(hm0[0], hm0[1], hm0[2],  hm0[3]);
  op[1] = make_float4(hm0[4], hm0[5], hm0[6],  hm0[7]);
  op[2] = make_float4(hm0[8], hm0[9], hm0[10], hm0[11]);
  op[3] = make_float4(hm1[0], hm1[1], hm1[2],  hm1[3]);
  op[4] = make_float4(hm1[4], hm1[5], hm1[6],  hm1[7]);
  op[5] = make_float4(hm1[8], hm1[9], hm1[10], hm1[11]);
  *(float2*)(outg + NBLK*NN*TT + row*NN + n0) = make_float2(c0, c1);
}

extern "C" void kernel_launch(void* const* d_in, const int* in_sizes, int n_in,
                              void* d_out, int out_size, void* d_ws, size_t ws_size,
                              hipStream_t stream)
{
  (void)in_sizes; (void)n_in; (void)out_size; (void)ws_size;
  // setup_inputs order: input, cell, adj, w1, a1, w2, a2, bias
  const float* xg    = (const float*)d_in[0];
  const float* cellg = (const float*)d_in[1];
  const float* w1g   = (const float*)d_in[3];
  const float* w2g   = (const float*)d_in[5];
  const float* biasg = (const float*)d_in[7];
  float* outg = (float*)d_out;
  u64* slots = (u64*)d_ws;

  // memset zeroes ONLY the L3 slots (slow mirrors + xsum). Fast slots are
  // self-scrubbed by their owning block (same-L2 overwrite is the only way
  // to reliably clear them).
  hipMemsetAsync(d_ws, 0, (size_t)(14*NBLK)*sizeof(u64), stream);
  glstm_fused<<<dim3(NBLK), dim3(NTHR), 0, stream>>>(xg, cellg, w1g, w2g, biasg, outg, slots);
}

// Round 13
// 40.990 us; speedup vs baseline: 3.8174x; 1.1293x over previous
//
#include <hip/hip_runtime.h>

typedef unsigned long long u64;

#define CC 32
#define NN 512
#define TT 12
#define NBLK 256     // one block per (batch, channel); == CU count
#define NTHR 256     // 2 n-elements per thread (proven shape)

__device__ __forceinline__ float eluf(float x){ return x>0.f ? x : (__expf(x)-1.f); }
__device__ __forceinline__ float elu3f(float x){ return eluf(eluf(eluf(x))); }
__device__ __forceinline__ float sigmf(float x){
  if (x>=0.f) return 1.f/(1.f+__expf(-x));
  float e=__expf(x); return e/(1.f+e);
}
__device__ __forceinline__ float tanhff(float x){
  return 1.f - 2.f/(__expf(2.f*x)+1.f);   // exact at saturation
}
__device__ __forceinline__ u64 pack_slot(unsigned tag, float v){
  return ((u64)tag<<32) | (u64)__float_as_uint(v);
}
__device__ __forceinline__ u64 ld_slot(u64* p){
  return __hip_atomic_load(p, __ATOMIC_RELAXED, __HIP_MEMORY_SCOPE_AGENT);
}
__device__ __forceinline__ void xch_slot(u64* p, u64 v){
  (void)__hip_atomic_exchange(p, v, __ATOMIC_RELAXED, __HIP_MEMORY_SCOPE_AGENT);
}
__device__ __forceinline__ float poll_slot(u64* p, unsigned want){
  u64 v = ld_slot(p);
  int guard = 0;
  while ((unsigned)(v>>32) != want){
    __builtin_amdgcn_s_sleep(1);
    v = ld_slot(p);
    if (++guard > 1000000) break;   // terminates instead of hanging
  }
  return __uint_as_float((unsigned)v);
}

__global__ __launch_bounds__(NTHR, 1)
void glstm_fused(const float* __restrict__ xg,     // (B,C,N,T)
                 const float* __restrict__ cellg,  // (B,C,N)
                 const float* __restrict__ w1g,    // (T,8,C,C)
                 const float* __restrict__ w2g,    // (T,8,C,C)
                 const float* __restrict__ biasg,  // (4,C,N,T)
                 float* __restrict__ outg,         // (B,C,N,T) ++ (B,C,N)
                 u64* slots)
{
  // 96KB bias tile -> 1 block/CU (proven residency for the spin pipeline)
  __shared__ float biasL[4][TT][NN];
  __shared__ float preS[2][4];       // parity-buffered gate pre-activations
  __shared__ float redS[2][4];       // parity-buffered csum wave-partials
  __shared__ float wpart[13][4];

  const int blk  = blockIdx.x;
  const int b    = blk >> 5;         // proven mapping (XCD-local mapping hurts)
  const int ch   = blk & 31;
  const int row  = blk;
  const int tid  = threadIdx.x;
  const int lane = tid & 63;
  const int wv   = tid >> 6;         // 0..3
  const int i0   = lane & 31;

  u64* cs_slot = slots;              // [2][NBLK] tagged csum, parity-buffered
  u64* xs_slot = slots + 2*NBLK;     // [TT][NBLK] tagged xsum, tag=1

  // ---- per-thread state: 2 n-elements ----
  const int n0 = 2*tid;
  float2 cc2 = *(const float2*)(cellg + row*NN + n0);
  float c0 = cc2.x, c1 = cc2.y;

  // ---- x rowsums per t + csum(state0) FIRST (publish gates the batch group) ----
  float xs[TT];
  #pragma unroll
  for (int t=0;t<TT;t++) xs[t]=0.f;
  const float* xrow = xg + row*NN*TT;
  #pragma unroll
  for (int half=0; half<2; half++){
    int n = tid + half*256;
    const float4* p = (const float4*)(xrow + n*TT);
    float4 v0=p[0], v1=p[1], v2=p[2];
    xs[0]+=v0.x;  xs[1]+=v0.y;  xs[2]+=v0.z;  xs[3]+=v0.w;
    xs[4]+=v1.x;  xs[5]+=v1.y;  xs[6]+=v1.z;  xs[7]+=v1.w;
    xs[8]+=v2.x;  xs[9]+=v2.y;  xs[10]+=v2.z; xs[11]+=v2.w;
  }
  float cp = c0 + c1;
  #pragma unroll
  for (int off=32; off>=1; off>>=1){
    #pragma unroll
    for (int t=0;t<TT;t++) xs[t] += __shfl_xor(xs[t], off, 64);
    cp += __shfl_xor(cp, off, 64);
  }
  if (lane == 0){
    #pragma unroll
    for (int t=0;t<TT;t++) wpart[t][wv] = xs[t];
    wpart[12][wv] = cp;
  }
  __syncthreads();
  if (tid < 13){
    float v = wpart[tid][0]+wpart[tid][1]+wpart[tid][2]+wpart[tid][3];
    if (tid < TT) xch_slot(&xs_slot[tid*NBLK + row], pack_slot(1u, v));
    else          xch_slot(&cs_slot[row],            pack_slot(1u, v));  // parity 0
  }

  // ---- bias -> LDS (after publish; overlaps peers' publish latency) ----
  #pragma unroll
  for (int k=0;k<4;k++){
    #pragma unroll
    for (int half=0; half<2; half++){
      int n = tid + half*256;
      const float4* p = (const float4*)(biasg + ((k*CC + ch)*NN + n)*TT);
      float4 v0=p[0], v1=p[1], v2=p[2];
      biasL[k][0][n]=v0.x;  biasL[k][1][n]=v0.y;  biasL[k][2][n]=v0.z;  biasL[k][3][n]=v0.w;
      biasL[k][4][n]=v1.x;  biasL[k][5][n]=v1.y;  biasL[k][6][n]=v1.z;  biasL[k][7][n]=v1.w;
      biasL[k][8][n]=v2.x;  biasL[k][9][n]=v2.y;  biasL[k][10][n]=v2.z; biasL[k][11][n]=v2.w;
    }
  }

  // ---- head assignment + weight double-buffer (t=0 now) ----
  const int m = wv + ((lane >> 5) << 2);   // lanes<32: x-heads 0-3; lanes>=32: c-heads 4-7
  float w1p[2][32];
  float w2p[2];
  {
    const float* w1m = w1g + m*CC*CC + i0;
    #pragma unroll
    for (int j=0;j<32;j++) w1p[0][j] = w1m[j*CC];
    w2p[0] = w2g[(m*CC + i0)*CC + ch];
  }

  // ---- BATCHED gather of ALL peer xsums: 12 independent loads per sweep
  //      (one vmcnt window ~= one L3 RTT) instead of 12 dependent poll_slot
  //      calls (~12 serial RTTs ~= 4-5us of pipeline-gating prologue). ----
  float zxr[TT];
  {
    u64 vv[TT];
    int guard = 0;
    for (;;){
      #pragma unroll
      for (int t=0;t<TT;t++)
        vv[t] = ld_slot(&xs_slot[t*NBLK + b*CC + i0]);   // independent loads
      unsigned okm = 1u;
      #pragma unroll
      for (int t=0;t<TT;t++) okm &= (unsigned)((vv[t]>>32) == 1u);
      if (__all(okm)) break;
      __builtin_amdgcn_s_sleep(1);
      if (++guard > 200000) break;   // terminates instead of hanging
    }
    #pragma unroll
    for (int t=0;t<TT;t++) zxr[t] = __uint_as_float((unsigned)vv[t]);
  }

  // ---- 12 sequential steps, fully unrolled, 2 barriers/step ----
  float hm0[TT], hm1[TT];
  #pragma unroll
  for (int s=0;s<TT;s++){
    // hop: all lanes poll this step's peer csum
    float csv = poll_slot(&cs_slot[(s&1)*NBLK + b*CC + i0], (unsigned)(s+1));
    float zs = (lane < 32) ? zxr[s] : csv;

    // head matvec from prefetched registers (no global loads post-poll)
    float pa = 0.f, pb = 0.f;
    #pragma unroll
    for (int j=0;j<16;j++){
      pa = fmaf(__shfl(zs, j,    32), w1p[s&1][j],    pa);
      pb = fmaf(__shfl(zs, j+16, 32), w1p[s&1][j+16], pb);
    }
    float s1 = pa + pb;
    float h1 = eluf(eluf(s1));
    float pp = h1 * w2p[s&1];
    #pragma unroll
    for (int off=16; off>=1; off>>=1) pp += __shfl_xor(pp, off, 32);
    float ov = elu3f(512.f*pp);
    float prew = ov + __shfl_xor(ov, 32, 64);      // x-head + c-head
    if (lane == 0) preS[s&1][wv] = prew;

    // bias -> regs before the barrier (gate phase = pure VALU)
    float b00 = biasL[0][s][n0], b01 = biasL[0][s][n0+1];
    float b10 = biasL[1][s][n0], b11 = biasL[1][s][n0+1];
    float b20 = biasL[2][s][n0], b21 = biasL[2][s][n0+1];
    float b30 = biasL[3][s][n0], b31 = biasL[3][s][n0+1];

    __syncthreads();   // B1: preS[s&1] ready
    const float g0 = preS[s&1][0], g1 = preS[s&1][1];
    const float g2 = preS[s&1][2], g3 = preS[s&1][3];

    float ig0 = sigmf(g0 + b00);
    float fg0 = sigmf(g1 + b10);
    float ct0 = tanhff(g3 + b30);
    float ig1 = sigmf(g0 + b01);
    float fg1 = sigmf(g1 + b11);
    float ct1 = tanhff(g3 + b31);
    c0 = fg0*c0 + ig0*ct0;
    c1 = fg1*c1 + ig1*ct1;

    if (s < TT-1){
      const int par = (s+1)&1;
      float csp = c0 + c1;
      #pragma unroll
      for (int off=32; off>=1; off>>=1) csp += __shfl_xor(csp, off, 64);
      if (lane == 0) redS[par][wv] = csp;
      __syncthreads(); // B2: redS ready (also fences preS for next parity reuse)
      if (tid == 0){
        float tot = redS[par][0]+redS[par][1]+redS[par][2]+redS[par][3];
        xch_slot(&cs_slot[par*NBLK + row], pack_slot((unsigned)(s+2), tot));
      }
      // prefetch next step's weights AFTER the publish point
      const float* w1m = w1g + ((s+1)*8 + m)*CC*CC + i0;
      #pragma unroll
      for (int j=0;j<32;j++) w1p[par][j] = w1m[j*CC];
      w2p[par] = w2g[(((s+1)*8 + m)*CC + i0)*CC + ch];
    }

    hm0[s] = sigmf(g2 + b20) * tanhff(c0);
    hm1[s] = sigmf(g2 + b21) * tanhff(c1);
  }

  // ---- coalesced epilogue: 2 n-rows x 12 t contiguous ----
  float4* op = (float4*)(outg + (row*NN + n0)*TT);
  op[0] = make_float4(hm0[0], hm0[1], hm0[2],  hm0[3]);
  op[1] = make_float4(hm0[4], hm0[5], hm0[6],  hm0[7]);
  op[2] = make_float4(hm0[8], hm0[9], hm0[10], hm0[11]);
  op[3] = make_float4(hm1[0], hm1[1], hm1[2],  hm1[3]);
  op[4] = make_float4(hm1[4], hm1[5], hm1[6],  hm1[7]);
  op[5] = make_float4(hm1[8], hm1[9], hm1[10], hm1[11]);
  *(float2*)(outg + NBLK*NN*TT + row*NN + n0) = make_float2(c0, c1);
}

extern "C" void kernel_launch(void* const* d_in, const int* in_sizes, int n_in,
                              void* d_out, int out_size, void* d_ws, size_t ws_size,
                              hipStream_t stream)
{
  (void)in_sizes; (void)n_in; (void)out_size; (void)ws_size;
  // setup_inputs order: input, cell, adj, w1, a1, w2, a2, bias
  const float* xg    = (const float*)d_in[0];
  const float* cellg = (const float*)d_in[1];
  const float* w1g   = (const float*)d_in[3];
  const float* w2g   = (const float*)d_in[5];
  const float* biasg = (const float*)d_in[7];
  float* outg = (float*)d_out;
  u64* slots = (u64*)d_ws;

  // reset sync tags every launch (ws is not re-poisoned between replays)
  hipMemsetAsync(d_ws, 0, (size_t)(2*NBLK + TT*NBLK)*sizeof(u64), stream);
  glstm_fused<<<dim3(NBLK), dim3(NTHR), 0, stream>>>(xg, cellg, w1g, w2g, biasg, outg, slots);
}